// Round 1
// baseline (476.478 us; speedup 1.0000x reference)
//
#include <hip/hip_runtime.h>
#include <math.h>

#define MUL0 64
#define MUL1 32
#define ROW_F 160          // floats per row of node_input / output
#define EPS2 1.0e-16f      // EPS^2
#define LOG2F_ 0.69314718055994531f

// ---------------------------------------------------------------------------
// Kernel 1: combine the three weight matrices per path into one, with the
// normalization constants folded in.
//   ws[0    .. 2048) : W0c (32x64)  = C0 * W_tp_0e @ W_lin_0e @ W_sc_0e
//   ws[2048 .. 4096) : W1c (64x32)  = C1 * W_tp_1o @ W_lin_1o @ W_sc_1o
// ---------------------------------------------------------------------------
__global__ void combine_weights(const float* __restrict__ Wtp0,   // 32x64
                                const float* __restrict__ Wtp1,   // 64x32
                                const float* __restrict__ Wlin0,  // 64x64
                                const float* __restrict__ Wlin1,  // 32x32
                                const float* __restrict__ Wsc0,   // 64x64
                                const float* __restrict__ Wsc1,   // 32x32
                                float* __restrict__ ws)
{
    __shared__ float tmp0[32 * 64];
    __shared__ float tmp1[64 * 32];
    const int t = threadIdx.x;

    // tmp0[u][w] = sum_k Wtp0[u][k] * Wlin0[k][w]   (u<32, w<64)
    for (int i = t; i < 32 * 64; i += 256) {
        int u = i >> 6, w = i & 63;
        float acc = 0.f;
        for (int k = 0; k < 64; ++k) acc += Wtp0[u * 64 + k] * Wlin0[k * 64 + w];
        tmp0[i] = acc;
    }
    // tmp1[u][w] = sum_k Wtp1[u][k] * Wlin1[k][w]   (u<64, w<32)
    for (int i = t; i < 64 * 32; i += 256) {
        int u = i >> 5, w = i & 31;
        float acc = 0.f;
        for (int k = 0; k < 32; ++k) acc += Wtp1[u * 32 + k] * Wlin1[k * 32 + w];
        tmp1[i] = acc;
    }
    __syncthreads();

    const float C0 = 1.0f / (sqrtf(96.0f) * 64.0f);   // 1/sqrt(3*MUL1)/sqrt(MUL0)/sqrt(MUL0)
    const float C1 = 1.0f / 256.0f;                   // 1/sqrt(MUL0)/sqrt(MUL1)/sqrt(MUL1)

    // W0c[u][w] = C0 * sum_k tmp0[u][k] * Wsc0[k][w]
    for (int i = t; i < 32 * 64; i += 256) {
        int u = i >> 6, w = i & 63;
        float acc = 0.f;
        for (int k = 0; k < 64; ++k) acc += tmp0[u * 64 + k] * Wsc0[k * 64 + w];
        ws[i] = C0 * acc;
    }
    // W1c[u][w] = C1 * sum_k tmp1[u][k] * Wsc1[k][w]
    for (int i = t; i < 64 * 32; i += 256) {
        int u = i >> 5, w = i & 31;
        float acc = 0.f;
        for (int k = 0; k < 32; ++k) acc += tmp1[u * 32 + k] * Wsc1[k * 32 + w];
        ws[2048 + i] = C1 * acc;
    }
}

// (softplus(n) - log 2) / n   for n > 0  (n >= 1e-8 always, ratio -> 0.5 as n->0)
__device__ __forceinline__ float ssp_over_n(float n)
{
    float sp = n + __logf(1.0f + __expf(-n)) - LOG2F_;
    return __fdividef(sp, n);
}

// ---------------------------------------------------------------------------
// Kernel 2: one row per thread.
// ---------------------------------------------------------------------------
__global__ __launch_bounds__(256)
void field_main(const float* __restrict__ in,     // N x 160
                const float* __restrict__ attr,   // N
                const float* __restrict__ field,  // N x 3
                const float* __restrict__ W0c,    // 32x64, scaled
                const float* __restrict__ W1c,    // 64x32, scaled
                float* __restrict__ out,          // N x 160
                int nrows)
{
    int row = blockIdx.x * 256 + threadIdx.x;
    if (row >= nrows) return;

    const float* rin  = in  + (size_t)row * ROW_F;
    float*       rout = out + (size_t)row * ROW_F;

    const float f0 = field[row * 3 + 0];
    const float f1 = field[row * 3 + 1];
    const float f2 = field[row * 3 + 2];
    const float a  = attr[row];
    const float af0 = a * f0, af1 = a * f1, af2 = a * f2;

    // ---- Phase A: s1[u] = a * sum_m x1[u][m] * f[m]   (a folded in) ----
    float s1[MUL1];
    {
        const float4* p4 = (const float4*)(rin + MUL0);
#pragma unroll
        for (int g = 0; g < 8; ++g) {
            float4 q0 = p4[3 * g + 0];
            float4 q1 = p4[3 * g + 1];
            float4 q2 = p4[3 * g + 2];
            s1[4 * g + 0] = q0.x * af0 + q0.y * af1 + q0.z * af2;
            s1[4 * g + 1] = q0.w * af0 + q1.x * af1 + q1.y * af2;
            s1[4 * g + 2] = q1.z * af0 + q1.w * af1 + q2.x * af2;
            s1[4 * g + 3] = q2.y * af0 + q2.z * af1 + q2.w * af2;
        }
    }

    // ---- Phase B: pw[w] = a * sum_u x0[u] * W1c[u][w] ----
    float pw[MUL1];
#pragma unroll
    for (int w = 0; w < MUL1; ++w) pw[w] = 0.f;
    {
        const float4* p4 = (const float4*)rin;
#pragma unroll
        for (int i = 0; i < 16; ++i) {
            float4 q = p4[i];
            float xv[4] = {q.x, q.y, q.z, q.w};
#pragma unroll
            for (int j = 0; j < 4; ++j) {
                const float xu = xv[j];
                const float* wrow = W1c + (4 * i + j) * MUL1;  // uniform address -> s_load
#pragma unroll
                for (int w = 0; w < MUL1; ++w) pw[w] += xu * wrow[w];
            }
        }
#pragma unroll
        for (int w = 0; w < MUL1; ++w) pw[w] *= a;
    }

    // ---- Phase C: z0 chunks of 16, fused with residual + gate + store ----
#pragma unroll
    for (int wc = 0; wc < MUL0; wc += 16) {
        float acc[16];
#pragma unroll
        for (int j = 0; j < 16; ++j) acc[j] = 0.f;
#pragma unroll
        for (int u = 0; u < MUL1; ++u) {
            const float su = s1[u];
            const float* wrow = W0c + u * MUL0 + wc;           // uniform address -> s_load
#pragma unroll
            for (int j = 0; j < 16; ++j) acc[j] += su * wrow[j];
        }
        const float4* px = (const float4*)(rin + wc);
        float4*       po = (float4*)(rout + wc);
#pragma unroll
        for (int v = 0; v < 4; ++v) {
            float4 x = px[v];
            float4 o;
            float r;
            r = x.x + acc[4 * v + 0]; o.x = r * ssp_over_n(sqrtf(r * r + EPS2));
            r = x.y + acc[4 * v + 1]; o.y = r * ssp_over_n(sqrtf(r * r + EPS2));
            r = x.z + acc[4 * v + 2]; o.z = r * ssp_over_n(sqrtf(r * r + EPS2));
            r = x.w + acc[4 * v + 3]; o.w = r * ssp_over_n(sqrtf(r * r + EPS2));
            po[v] = o;
        }
    }

    // ---- Phase D: r1[u][m] = x1[u][m] + pw[u]*f[m]; gate by vector norm ----
#pragma unroll
    for (int g = 0; g < 8; ++g) {
        const float4* px = (const float4*)(rin + MUL0 + 12 * g);
        float4 q0 = px[0], q1 = px[1], q2 = px[2];
        float r[12];
        const float p0 = pw[4 * g + 0], p1 = pw[4 * g + 1];
        const float p2 = pw[4 * g + 2], p3 = pw[4 * g + 3];
        r[0]  = q0.x + p0 * f0;  r[1]  = q0.y + p0 * f1;  r[2]  = q0.z + p0 * f2;
        r[3]  = q0.w + p1 * f0;  r[4]  = q1.x + p1 * f1;  r[5]  = q1.y + p1 * f2;
        r[6]  = q1.z + p2 * f0;  r[7]  = q1.w + p2 * f1;  r[8]  = q2.x + p2 * f2;
        r[9]  = q2.y + p3 * f0;  r[10] = q2.z + p3 * f1;  r[11] = q2.w + p3 * f2;
#pragma unroll
        for (int k = 0; k < 4; ++k) {
            float n = sqrtf(r[3 * k] * r[3 * k] + r[3 * k + 1] * r[3 * k + 1] +
                            r[3 * k + 2] * r[3 * k + 2] + EPS2);
            float ratio = ssp_over_n(n);
            r[3 * k] *= ratio; r[3 * k + 1] *= ratio; r[3 * k + 2] *= ratio;
        }
        float4* po = (float4*)(rout + MUL0 + 12 * g);
        po[0] = make_float4(r[0], r[1], r[2], r[3]);
        po[1] = make_float4(r[4], r[5], r[6], r[7]);
        po[2] = make_float4(r[8], r[9], r[10], r[11]);
    }
}

extern "C" void kernel_launch(void* const* d_in, const int* in_sizes, int n_in,
                              void* d_out, int out_size, void* d_ws, size_t ws_size,
                              hipStream_t stream)
{
    const float* node_input = (const float*)d_in[0];
    const float* node_attr  = (const float*)d_in[1];
    const float* field      = (const float*)d_in[2];
    const float* Wtp0       = (const float*)d_in[3];
    const float* Wtp1       = (const float*)d_in[4];
    const float* Wlin0      = (const float*)d_in[5];
    const float* Wlin1      = (const float*)d_in[6];
    const float* Wsc0       = (const float*)d_in[7];
    const float* Wsc1       = (const float*)d_in[8];
    float* out = (float*)d_out;
    float* ws  = (float*)d_ws;

    const int nrows = in_sizes[0] / ROW_F;   // 200000

    hipLaunchKernelGGL(combine_weights, dim3(1), dim3(256), 0, stream,
                       Wtp0, Wtp1, Wlin0, Wlin1, Wsc0, Wsc1, ws);

    const int nb = (nrows + 255) / 256;
    hipLaunchKernelGGL(field_main, dim3(nb), dim3(256), 0, stream,
                       node_input, node_attr, field, ws, ws + 2048, out, nrows);
}

// Round 2
// 459.094 us; speedup vs baseline: 1.0379x; 1.0379x over previous
//
#include <hip/hip_runtime.h>
#include <math.h>

#define MUL0 64
#define MUL1 32
#define ROW_F 160          // floats per row of node_input / output
#define EPS2 1.0e-16f      // EPS^2
#define LOG2F_ 0.69314718055994531f
#define LP 65              // LDS transpose pad stride (65 % 32 == 1 -> conflict-free-ish)

// ---------------------------------------------------------------------------
// Kernel 1: combine the three weight matrices per path into one, with the
// normalization constants folded in.
//   ws[0    .. 2048) : W0c (32x64)  = C0 * W_tp_0e @ W_lin_0e @ W_sc_0e
//   ws[2048 .. 4096) : W1c (64x32)  = C1 * W_tp_1o @ W_lin_1o @ W_sc_1o
// ---------------------------------------------------------------------------
__global__ void combine_weights(const float* __restrict__ Wtp0,   // 32x64
                                const float* __restrict__ Wtp1,   // 64x32
                                const float* __restrict__ Wlin0,  // 64x64
                                const float* __restrict__ Wlin1,  // 32x32
                                const float* __restrict__ Wsc0,   // 64x64
                                const float* __restrict__ Wsc1,   // 32x32
                                float* __restrict__ ws)
{
    __shared__ float tmp0[32 * 64];
    __shared__ float tmp1[64 * 32];
    const int t = threadIdx.x;

    for (int i = t; i < 32 * 64; i += 256) {
        int u = i >> 6, w = i & 63;
        float acc = 0.f;
        for (int k = 0; k < 64; ++k) acc += Wtp0[u * 64 + k] * Wlin0[k * 64 + w];
        tmp0[i] = acc;
    }
    for (int i = t; i < 64 * 32; i += 256) {
        int u = i >> 5, w = i & 31;
        float acc = 0.f;
        for (int k = 0; k < 32; ++k) acc += Wtp1[u * 32 + k] * Wlin1[k * 32 + w];
        tmp1[i] = acc;
    }
    __syncthreads();

    const float C0 = 1.0f / (sqrtf(96.0f) * 64.0f);
    const float C1 = 1.0f / 256.0f;

    for (int i = t; i < 32 * 64; i += 256) {
        int u = i >> 6, w = i & 63;
        float acc = 0.f;
        for (int k = 0; k < 64; ++k) acc += tmp0[u * 64 + k] * Wsc0[k * 64 + w];
        ws[i] = C0 * acc;
    }
    for (int i = t; i < 64 * 32; i += 256) {
        int u = i >> 5, w = i & 31;
        float acc = 0.f;
        for (int k = 0; k < 32; ++k) acc += tmp1[u * 32 + k] * Wsc1[k * 32 + w];
        ws[2048 + i] = C1 * acc;
    }
}

// (softplus(n) - log 2) / n   for n > 0
__device__ __forceinline__ float ssp_over_n(float n)
{
    float sp = n + __logf(1.0f + __expf(-n)) - LOG2F_;
    return __fdividef(sp, n);
}

// ---------------------------------------------------------------------------
// LDS transpose staging: one wave (64 threads) <-> 64 rows x W cols.
// Global side is fully coalesced float4; compute side is one-row-per-lane.
// buf layout: [col][row] with row-stride LP=65 (bank-friendly).
// ---------------------------------------------------------------------------
template<int W>
__device__ __forceinline__ void stage_in(const float* __restrict__ g, float* buf,
                                         int lane, int rmax, float* dst)
{
    constexpr int NF4 = W / 4;
    __syncthreads();                       // WAR vs previous buf use
#pragma unroll
    for (int k = 0; k < NF4; ++k) {
        int id = k * 64 + lane;
        int r = id / NF4, gg = id % NF4;
        int rr = r <= rmax ? r : rmax;     // clamp (never taken when nrows%64==0)
        float4 v = *(const float4*)(g + rr * ROW_F + 4 * gg);
        buf[(4 * gg + 0) * LP + r] = v.x;
        buf[(4 * gg + 1) * LP + r] = v.y;
        buf[(4 * gg + 2) * LP + r] = v.z;
        buf[(4 * gg + 3) * LP + r] = v.w;
    }
    __syncthreads();
#pragma unroll
    for (int c = 0; c < W; ++c) dst[c] = buf[c * LP + lane];
}

template<int W>
__device__ __forceinline__ void stage_out(float* __restrict__ g, float* buf,
                                          int lane, int rmax, const float* src)
{
    constexpr int NF4 = W / 4;
    __syncthreads();                       // WAR vs previous buf reads
#pragma unroll
    for (int c = 0; c < W; ++c) buf[c * LP + lane] = src[c];
    __syncthreads();
#pragma unroll
    for (int k = 0; k < NF4; ++k) {
        int id = k * 64 + lane;
        int r = id / NF4, gg = id % NF4;
        int rr = r <= rmax ? r : rmax;     // duplicate rows write identical data
        float4 v;
        v.x = buf[(4 * gg + 0) * LP + r];
        v.y = buf[(4 * gg + 1) * LP + r];
        v.z = buf[(4 * gg + 2) * LP + r];
        v.w = buf[(4 * gg + 3) * LP + r];
        *(float4*)(g + rr * ROW_F + 4 * gg) = v;
    }
}

// ---------------------------------------------------------------------------
// Kernel 2: one wave per 64 rows; one row per lane; single streaming pass.
// Weights are thread-uniform -> scalar loads + SGPR-operand FMAs.
// ---------------------------------------------------------------------------
__global__ __launch_bounds__(64)
void field_main(const float* __restrict__ in,     // N x 160
                const float* __restrict__ attr,   // N
                const float* __restrict__ field,  // N x 3
                const float* __restrict__ W0c,    // 32x64, scaled
                const float* __restrict__ W1c,    // 64x32, scaled
                float* __restrict__ out,          // N x 160
                int nrows)
{
    __shared__ float buf[48 * LP];
    const int lane = threadIdx.x;
    const int r0 = blockIdx.x * 64;
    if (r0 >= nrows) return;
    const int rmax = min(63, nrows - 1 - r0);
    const int rowe = r0 + min(lane, rmax);

    const float a  = attr[rowe];
    const float f0 = field[3 * rowe + 0];
    const float f1 = field[3 * rowe + 1];
    const float f2 = field[3 * rowe + 2];
    const float af0 = a * f0, af1 = a * f1, af2 = a * f2;

    const float* gin  = in  + (size_t)r0 * ROW_F;
    float*       gout = out + (size_t)r0 * ROW_F;

    // ---- x0 (cols 0..64) into registers via coalesced staging ----
    float x0r[64];
    stage_in<32>(gin,      buf, lane, rmax, x0r);
    stage_in<32>(gin + 32, buf, lane, rmax, x0r + 32);

    // ---- pw[w] = a * sum_u x0[u] * W1c[u][w]  (scalar weights) ----
    float pw[32];
#pragma unroll
    for (int w = 0; w < 32; ++w) pw[w] = 0.f;
#pragma unroll
    for (int u = 0; u < 64; ++u) {
        const float xu = x0r[u];
        const float* wr = W1c + u * 32;    // thread-uniform -> s_load
#pragma unroll
        for (int w = 0; w < 32; ++w) pw[w] += xu * wr[w];
    }
#pragma unroll
    for (int w = 0; w < 32; ++w) pw[w] *= a;

    // ---- stream x1 (cols 64..160) in two 48-col chunks (16 u's each):
    //      accumulate s1, emit gated o1 immediately ----
    float s1[32];
#pragma unroll
    for (int ch = 0; ch < 2; ++ch) {
        float c[48];
        stage_in<48>(gin + 64 + 48 * ch, buf, lane, rmax, c);
#pragma unroll
        for (int i = 0; i < 16; ++i) {
            const int u = 16 * ch + i;
            const float m0 = c[3 * i], m1 = c[3 * i + 1], m2 = c[3 * i + 2];
            s1[u] = m0 * af0 + m1 * af1 + m2 * af2;
            const float p = pw[u];
            float q0 = m0 + p * f0;
            float q1 = m1 + p * f1;
            float q2 = m2 + p * f2;
            float n = sqrtf(q0 * q0 + q1 * q1 + q2 * q2 + EPS2);
            float t = ssp_over_n(n);
            c[3 * i] = q0 * t; c[3 * i + 1] = q1 * t; c[3 * i + 2] = q2 * t;
        }
        stage_out<48>(gout + 64 + 48 * ch, buf, lane, rmax, c);
    }

    // ---- z0 = s1 @ W0c (scalar weights); o0 = gate(x0 + z0) ----
#pragma unroll
    for (int wc = 0; wc < 2; ++wc) {
        float acc[32];
#pragma unroll
        for (int j = 0; j < 32; ++j) acc[j] = 0.f;
#pragma unroll
        for (int u = 0; u < 32; ++u) {
            const float su = s1[u];
            const float* wr = W0c + u * 64 + 32 * wc;   // thread-uniform -> s_load
#pragma unroll
            for (int j = 0; j < 32; ++j) acc[j] += su * wr[j];
        }
#pragma unroll
        for (int j = 0; j < 32; ++j) {
            float r = x0r[32 * wc + j] + acc[j];
            float n = sqrtf(r * r + EPS2);
            acc[j] = r * ssp_over_n(n);
        }
        stage_out<32>(gout + 32 * wc, buf, lane, rmax, acc);
    }
}

extern "C" void kernel_launch(void* const* d_in, const int* in_sizes, int n_in,
                              void* d_out, int out_size, void* d_ws, size_t ws_size,
                              hipStream_t stream)
{
    const float* node_input = (const float*)d_in[0];
    const float* node_attr  = (const float*)d_in[1];
    const float* field      = (const float*)d_in[2];
    const float* Wtp0       = (const float*)d_in[3];
    const float* Wtp1       = (const float*)d_in[4];
    const float* Wlin0      = (const float*)d_in[5];
    const float* Wlin1      = (const float*)d_in[6];
    const float* Wsc0       = (const float*)d_in[7];
    const float* Wsc1       = (const float*)d_in[8];
    float* out = (float*)d_out;
    float* ws  = (float*)d_ws;

    const int nrows = in_sizes[0] / ROW_F;   // 200000

    hipLaunchKernelGGL(combine_weights, dim3(1), dim3(256), 0, stream,
                       Wtp0, Wtp1, Wlin0, Wlin1, Wsc0, Wsc1, ws);

    const int nb = (nrows + 63) / 64;
    hipLaunchKernelGGL(field_main, dim3(nb), dim3(64), 0, stream,
                       node_input, node_attr, field, ws, ws + 2048, out, nrows);
}

// Round 3
// 415.377 us; speedup vs baseline: 1.1471x; 1.1052x over previous
//
#include <hip/hip_runtime.h>
#include <math.h>

#define MUL0 64
#define MUL1 32
#define ROW_F 160          // floats per row of node_input / output
#define EPS2 1.0e-16f      // EPS^2
#define LOG2F_ 0.69314718055994531f
#define LP 65              // LDS transpose pad stride (65 % 32 == 1 -> 2-way max, free)
#define WPB 3              // waves per block
#define TPB (WPB * 64)

// ---------------------------------------------------------------------------
// Kernel 1: combine the three weight matrices per path into one, with the
// normalization constants folded in.
//   ws[0    .. 2048) : W0c (32x64)  = C0 * W_tp_0e @ W_lin_0e @ W_sc_0e
//   ws[2048 .. 4096) : W1c (64x32)  = C1 * W_tp_1o @ W_lin_1o @ W_sc_1o
// ---------------------------------------------------------------------------
__global__ void combine_weights(const float* __restrict__ Wtp0,   // 32x64
                                const float* __restrict__ Wtp1,   // 64x32
                                const float* __restrict__ Wlin0,  // 64x64
                                const float* __restrict__ Wlin1,  // 32x32
                                const float* __restrict__ Wsc0,   // 64x64
                                const float* __restrict__ Wsc1,   // 32x32
                                float* __restrict__ ws)
{
    __shared__ float tmp0[32 * 64];
    __shared__ float tmp1[64 * 32];
    const int t = threadIdx.x;

    for (int i = t; i < 32 * 64; i += 256) {
        int u = i >> 6, w = i & 63;
        float acc = 0.f;
        for (int k = 0; k < 64; ++k) acc += Wtp0[u * 64 + k] * Wlin0[k * 64 + w];
        tmp0[i] = acc;
    }
    for (int i = t; i < 64 * 32; i += 256) {
        int u = i >> 5, w = i & 31;
        float acc = 0.f;
        for (int k = 0; k < 32; ++k) acc += Wtp1[u * 32 + k] * Wlin1[k * 32 + w];
        tmp1[i] = acc;
    }
    __syncthreads();

    const float C0 = 1.0f / (sqrtf(96.0f) * 64.0f);
    const float C1 = 1.0f / 256.0f;

    for (int i = t; i < 32 * 64; i += 256) {
        int u = i >> 6, w = i & 63;
        float acc = 0.f;
        for (int k = 0; k < 64; ++k) acc += tmp0[u * 64 + k] * Wsc0[k * 64 + w];
        ws[i] = C0 * acc;
    }
    for (int i = t; i < 64 * 32; i += 256) {
        int u = i >> 5, w = i & 31;
        float acc = 0.f;
        for (int k = 0; k < 32; ++k) acc += tmp1[u * 32 + k] * Wsc1[k * 32 + w];
        ws[2048 + i] = C1 * acc;
    }
}

// (softplus(n) - log 2) / n   for n > 0
__device__ __forceinline__ float ssp_over_n(float n)
{
    float sp = n + __logf(1.0f + __expf(-n)) - LOG2F_;
    return __fdividef(sp, n);
}

// Wave-local fence: buffer is wave-private and the DS pipe is in-order per
// wave, so we only need to stop the compiler from reordering LDS accesses.
__device__ __forceinline__ void wave_fence()
{
    __asm__ volatile("" ::: "memory");
    __builtin_amdgcn_wave_barrier();
}

// ---------------------------------------------------------------------------
// LDS transpose staging: one wave (64 lanes) <-> 64 rows x W cols.
// Global side is fully coalesced float4 (explicitly batched so all loads are
// in flight together); compute side is one-row-per-lane.
// buf layout: [col][row], row-stride LP=65.
// ---------------------------------------------------------------------------
template<int W>
__device__ __forceinline__ void stage_in(const float* __restrict__ g, float* buf,
                                         int lane, int rmax, float* dst)
{
    constexpr int NF4 = W / 4;
    float4 v[NF4];
#pragma unroll
    for (int k = 0; k < NF4; ++k) {
        int id = k * 64 + lane;
        int r = id / NF4, gg = id % NF4;
        int rr = r <= rmax ? r : rmax;     // clamp (dup rows, benign)
        v[k] = *(const float4*)(g + rr * ROW_F + 4 * gg);
    }
    wave_fence();                          // WAR vs previous buf consumers
#pragma unroll
    for (int k = 0; k < NF4; ++k) {
        int id = k * 64 + lane;
        int r = id / NF4, gg = id % NF4;
        buf[(4 * gg + 0) * LP + r] = v[k].x;
        buf[(4 * gg + 1) * LP + r] = v[k].y;
        buf[(4 * gg + 2) * LP + r] = v[k].z;
        buf[(4 * gg + 3) * LP + r] = v[k].w;
    }
    wave_fence();
#pragma unroll
    for (int c = 0; c < W; ++c) dst[c] = buf[c * LP + lane];
}

template<int W>
__device__ __forceinline__ void stage_out(float* __restrict__ g, float* buf,
                                          int lane, int rmax, const float* src)
{
    constexpr int NF4 = W / 4;
    wave_fence();                          // WAR vs previous buf reads
#pragma unroll
    for (int c = 0; c < W; ++c) buf[c * LP + lane] = src[c];
    wave_fence();
#pragma unroll
    for (int k = 0; k < NF4; ++k) {
        int id = k * 64 + lane;
        int r = id / NF4, gg = id % NF4;
        int rr = r <= rmax ? r : rmax;     // dup rows write identical data
        float4 v;
        v.x = buf[(4 * gg + 0) * LP + r];
        v.y = buf[(4 * gg + 1) * LP + r];
        v.z = buf[(4 * gg + 2) * LP + r];
        v.w = buf[(4 * gg + 3) * LP + r];
        *(float4*)(g + rr * ROW_F + 4 * gg) = v;
    }
}

// ---------------------------------------------------------------------------
// Kernel 2: 3 waves/block; each wave owns 64 rows, one row per lane.
// Weights staged to LDS once per block; compute reads them as uniform-address
// float4 broadcasts (no scalar loads, no bank conflicts).
// ---------------------------------------------------------------------------
__global__ __launch_bounds__(TPB)
void field_main(const float* __restrict__ in,     // N x 160
                const float* __restrict__ attr,   // N
                const float* __restrict__ field,  // N x 3
                const float* __restrict__ Wg,     // 4096 floats: W0c | W1c
                float* __restrict__ out,          // N x 160
                int nrows)
{
    __shared__ __align__(16) float wlds[4096];    // W0c[32*64] | W1c[64*32]
    __shared__ float tbuf[WPB][48 * LP];

    const int tid = threadIdx.x;

    // ---- one-time block-level weight staging ----
    {
        const float4* src = (const float4*)Wg;
        float4* dst = (float4*)wlds;
        for (int i = tid; i < 1024; i += TPB) dst[i] = src[i];
    }
    __syncthreads();                               // only block-wide barrier

    const int wv = tid >> 6, lane = tid & 63;
    int r0 = (blockIdx.x * WPB + wv) * 64;
    if (r0 > nrows - 64) r0 = nrows - 64;          // overflow waves: dup work
    if (r0 < 0) r0 = 0;
    const int rmax = min(63, nrows - 1 - r0);
    const int rowe = r0 + min(lane, rmax);

    const float a  = attr[rowe];
    const float f0 = field[3 * rowe + 0];
    const float f1 = field[3 * rowe + 1];
    const float f2 = field[3 * rowe + 2];
    const float af0 = a * f0, af1 = a * f1, af2 = a * f2;

    const float* gin  = in  + (size_t)r0 * ROW_F;
    float*       gout = out + (size_t)r0 * ROW_F;
    float* buf = tbuf[wv];

    // ---- x0 (cols 0..64) into registers via coalesced staging ----
    float x0r[64];
    stage_in<32>(gin,      buf, lane, rmax, x0r);
    stage_in<32>(gin + 32, buf, lane, rmax, x0r + 32);

    // ---- pw[w] = a * sum_u x0[u] * W1c[u][w]  (LDS broadcast weights) ----
    float pw[32];
#pragma unroll
    for (int w = 0; w < 32; ++w) pw[w] = 0.f;
    for (int u = 0; u < 64; ++u) {
        const float xu = x0r[u];
        const float4* wr = (const float4*)&wlds[2048 + u * 32];
#pragma unroll
        for (int j = 0; j < 8; ++j) {
            float4 t = wr[j];
            pw[4 * j + 0] += xu * t.x;
            pw[4 * j + 1] += xu * t.y;
            pw[4 * j + 2] += xu * t.z;
            pw[4 * j + 3] += xu * t.w;
        }
    }
#pragma unroll
    for (int w = 0; w < 32; ++w) pw[w] *= a;

    // ---- stream x1 (cols 64..160) in two 48-col chunks (16 u's each):
    //      accumulate s1, emit gated o1 immediately ----
    float s1[32];
#pragma unroll
    for (int ch = 0; ch < 2; ++ch) {
        float c[48];
        stage_in<48>(gin + 64 + 48 * ch, buf, lane, rmax, c);
#pragma unroll
        for (int i = 0; i < 16; ++i) {
            const int u = 16 * ch + i;
            const float m0 = c[3 * i], m1 = c[3 * i + 1], m2 = c[3 * i + 2];
            s1[u] = m0 * af0 + m1 * af1 + m2 * af2;
            const float p = pw[u];
            float q0 = m0 + p * f0;
            float q1 = m1 + p * f1;
            float q2 = m2 + p * f2;
            float n = sqrtf(q0 * q0 + q1 * q1 + q2 * q2 + EPS2);
            float t = ssp_over_n(n);
            c[3 * i] = q0 * t; c[3 * i + 1] = q1 * t; c[3 * i + 2] = q2 * t;
        }
        stage_out<48>(gout + 64 + 48 * ch, buf, lane, rmax, c);
    }

    // ---- z0 = s1 @ W0c (LDS broadcast weights); o0 = gate(x0 + z0) ----
#pragma unroll
    for (int wc = 0; wc < 2; ++wc) {
        float acc[32];
#pragma unroll
        for (int j = 0; j < 32; ++j) acc[j] = 0.f;
        for (int u = 0; u < 32; ++u) {
            const float su = s1[u];
            const float4* wr = (const float4*)&wlds[u * 64 + 32 * wc];
#pragma unroll
            for (int j = 0; j < 8; ++j) {
                float4 t = wr[j];
                acc[4 * j + 0] += su * t.x;
                acc[4 * j + 1] += su * t.y;
                acc[4 * j + 2] += su * t.z;
                acc[4 * j + 3] += su * t.w;
            }
        }
#pragma unroll
        for (int j = 0; j < 32; ++j) {
            float r = x0r[32 * wc + j] + acc[j];
            float n = sqrtf(r * r + EPS2);
            acc[j] = r * ssp_over_n(n);
        }
        stage_out<32>(gout + 32 * wc, buf, lane, rmax, acc);
    }
}

extern "C" void kernel_launch(void* const* d_in, const int* in_sizes, int n_in,
                              void* d_out, int out_size, void* d_ws, size_t ws_size,
                              hipStream_t stream)
{
    const float* node_input = (const float*)d_in[0];
    const float* node_attr  = (const float*)d_in[1];
    const float* field      = (const float*)d_in[2];
    const float* Wtp0       = (const float*)d_in[3];
    const float* Wtp1       = (const float*)d_in[4];
    const float* Wlin0      = (const float*)d_in[5];
    const float* Wlin1      = (const float*)d_in[6];
    const float* Wsc0       = (const float*)d_in[7];
    const float* Wsc1       = (const float*)d_in[8];
    float* out = (float*)d_out;
    float* ws  = (float*)d_ws;

    const int nrows = in_sizes[0] / ROW_F;   // 200000

    hipLaunchKernelGGL(combine_weights, dim3(1), dim3(256), 0, stream,
                       Wtp0, Wtp1, Wlin0, Wlin1, Wsc0, Wsc1, ws);

    const int nwaves = (nrows + 63) / 64;
    const int nb = (nwaves + WPB - 1) / WPB;
    hipLaunchKernelGGL(field_main, dim3(nb), dim3(TPB), 0, stream,
                       node_input, node_attr, field, ws, out, nrows);
}